// Round 12
// baseline (197.237 us; speedup 1.0000x reference)
//
#include <hip/hip_runtime.h>
#include <hip/hip_bf16.h>
#include <stdint.h>

#define TOKENS 2048
#define DD 1024
#define HH 2048
#define NE 8
#define PAD 64
#define RP_CAP 2560   // 2048 + 8*63 rounded up to 64

typedef float f32x4 __attribute__((ext_vector_type(4)));
typedef short bf16x8 __attribute__((ext_vector_type(8)));
typedef unsigned int u32;

__device__ __forceinline__ unsigned short f2bf(float f) {
    union { float f; u32 u; } v; v.f = f;
    u32 u = v.u;
    return (unsigned short)((u + 0x7fffu + ((u >> 16) & 1u)) >> 16);
}

// ---------------- routing: expert per token, padded segments (64-aligned), perm ----------------
__global__ __launch_bounds__(256) void k_route(const int* __restrict__ orig,
                                               const int* __restrict__ hmap,
                                               int* __restrict__ hdr) {
    __shared__ int s_e[TOKENS];
    __shared__ int s_cnt[NE];
    __shared__ int s_off[NE];
    int tid = threadIdx.x;
    if (tid < NE) s_cnt[tid] = 0;
    __syncthreads();
    for (int t = tid; t < TOKENS; t += 256) {
        int e = hmap[orig[t]];
        s_e[t] = e;
        atomicAdd(&s_cnt[e], 1);
    }
    __syncthreads();
    if (tid == 0) {
        int run = 0;
        for (int e = 0; e < NE; ++e) {
            s_off[e] = run;
            hdr[e] = s_cnt[e];
            hdr[8 + e] = run;
            run += ((s_cnt[e] + PAD - 1) / PAD) * PAD;
        }
        hdr[16] = run;
    }
    __syncthreads();
    int* perm = hdr + 64;
    for (int r = tid; r < RP_CAP; r += 256) perm[r] = -1;
    if (tid < NE) s_cnt[tid] = 0;
    __syncthreads();
    for (int t = tid; t < TOKENS; t += 256) {
        int e = s_e[t];
        int pos = s_off[e] + atomicAdd(&s_cnt[e], 1);
        perm[pos] = t;
    }
}

// ---------------- gather x -> bf16 permuted padded layout ----------------
__global__ __launch_bounds__(256) void k_gather(const float* __restrict__ x,
                                                const int* __restrict__ hdr,
                                                unsigned short* __restrict__ xp) {
    int r = blockIdx.x;
    int t = hdr[64 + r];  // perm
    int tid = threadIdx.x;
    ushort4* dst = (ushort4*)(xp + (size_t)r * DD);
    if (t >= 0) {
        const float4* src = (const float4*)(x + (size_t)t * DD);
        float4 v = src[tid];
        ushort4 o;
        o.x = f2bf(v.x); o.y = f2bf(v.y); o.z = f2bf(v.z); o.w = f2bf(v.w);
        dst[tid] = o;
    } else {
        ushort4 z; z.x = 0; z.y = 0; z.z = 0; z.w = 0;
        dst[tid] = z;
    }
}

// ---------------- init: out[t][:] = b2[expert(t)][:] (bias pre-seed for GEMM2 atomics) ----
__global__ __launch_bounds__(256) void k_init(const int* __restrict__ orig,
                                              const int* __restrict__ hmap,
                                              const float* __restrict__ b2,
                                              float* __restrict__ out) {
    int t = blockIdx.x;
    int e = hmap[orig[t]];
    f32x4 b = ((const f32x4*)(b2 + (size_t)e * DD))[threadIdx.x];
    ((f32x4*)(out + (size_t)t * DD))[threadIdx.x] = b;
}

// ---------------- weight-stationary panel GEMM ----------------
// Block = one weight panel: 64 cols x 1024 K (bf16, 128 KB LDS), staged ONCE.
// 512 threads = 8 waves: wave (mg = w>>2, cg = w&3). After ONE __syncthreads, each
// wave independently runs the M-loop over its expert's 64-row tiles:
//   A-fragments from GLOBAL (ring-4 named regs, prefetch distance 3, no LDS),
//   B-fragments from the LDS panel (ds_read_b128, slot^(col&7) swizzle, ~2-way = free),
//   2 MFMA per 32-K step. ZERO barriers / vmcnt choreography in the hot loop.
// L1 epilogue: relu(acc+b1) -> hbuf bf16. L2 (K-split x2): atomicAdd f32 partials
// onto bias-seeded out (guarded by perm).
template<int KDIM, int NDIM, int NSPLIT, bool L2EPI>
__global__ __launch_bounds__(512, 1) void k_panel(const unsigned short* __restrict__ A,
                                                  const float* __restrict__ W,
                                                  const float* __restrict__ bias,
                                                  const int* __restrict__ hdr,
                                                  unsigned short* __restrict__ hout,
                                                  float* __restrict__ out) {
    int e  = blockIdx.y / NSPLIT;
    int ks = blockIdx.y % NSPLIT;
    int koff = ks * 1024;
    int n0 = blockIdx.x * 64;
    const float* Wg = W + (size_t)e * NDIM * KDIM;

    __shared__ __align__(16) unsigned short P[64 * 1024];   // 128 KB panel

    int tid = threadIdx.x;

    // ---- stage panel: 64 rows x 128 16B-slots, coalesced f32 reads, swizzled ds_write ----
#pragma unroll
    for (int i = 0; i < 16; ++i) {
        int sg = i * 512 + tid;           // slot id in [0, 8192)
        int row = sg >> 7;                // [0,64)
        int s   = sg & 127;               // 16B slot within row
        const float* gp = Wg + (size_t)(n0 + row) * KDIM + koff + s * 8;
        f32x4 v0 = *(const f32x4*)gp;
        f32x4 v1 = *(const f32x4*)(gp + 4);
        union { bf16x8 v; __hip_bfloat162 h2[4]; } o;
        o.h2[0] = __float22bfloat162_rn(make_float2(v0[0], v0[1]));
        o.h2[1] = __float22bfloat162_rn(make_float2(v0[2], v0[3]));
        o.h2[2] = __float22bfloat162_rn(make_float2(v1[0], v1[1]));
        o.h2[3] = __float22bfloat162_rn(make_float2(v1[2], v1[3]));
        *(bf16x8*)&P[row * 1024 + (s ^ (row & 7)) * 8] = o.v;
    }
    __syncthreads();   // the only block-wide sync

    int w = tid >> 6, lane = tid & 63;
    int mg = w >> 2, cg = w & 3;
    int fr = lane & 15, hi = lane >> 4;
    int colb = cg * 16 + fr;              // panel col owned by this lane
    int cx = colb & 7;
    const unsigned short* Pc = &P[colb * 1024];

    float bv = 0.f;
    if constexpr (!L2EPI) bv = bias[(size_t)e * NDIM + n0 + colb];

    int seg_lo = hdr[8 + e];
    int seg_hi = hdr[8 + e + 1];          // e==7 -> hdr[16]
    const int* perm = hdr + 64;

    for (int r0 = seg_lo; r0 < seg_hi; r0 += 64) {
        // lane A base: row (r0 + mg*32 + fr), m=1 adds 16*KDIM
        const unsigned short* Ab = A + (size_t)(r0 + mg * 32 + fr) * KDIM + koff + hi * 8;

        f32x4 a0 = f32x4{0.f, 0.f, 0.f, 0.f};
        f32x4 a1 = f32x4{0.f, 0.f, 0.f, 0.f};
        bf16x8 afr[4][2];                 // ring-4 prefetch buffers (static-indexed)
#pragma unroll
        for (int s = 0; s < 3; ++s) {
            afr[s][0] = *(const bf16x8*)(Ab + s * 32);
            afr[s][1] = *(const bf16x8*)(Ab + 16 * KDIM + s * 32);
        }
#pragma unroll
        for (int s = 0; s < 32; ++s) {
            if (s + 3 < 32) {
                afr[(s + 3) & 3][0] = *(const bf16x8*)(Ab + (s + 3) * 32);
                afr[(s + 3) & 3][1] = *(const bf16x8*)(Ab + 16 * KDIM + (s + 3) * 32);
            }
            int slot = s * 4 + hi;
            bf16x8 bfr = *(const bf16x8*)&Pc[(slot ^ cx) * 8];
            a0 = __builtin_amdgcn_mfma_f32_16x16x32_bf16(afr[s & 3][0], bfr, a0, 0, 0, 0);
            a1 = __builtin_amdgcn_mfma_f32_16x16x32_bf16(afr[s & 3][1], bfr, a1, 0, 0, 0);
        }

        // ---- per-M-tile epilogue: D row = hi*4+r (+m*16), D col = fr ----
        int rb = r0 + mg * 32 + hi * 4;
        int cgcol = n0 + colb;
        if constexpr (!L2EPI) {
#pragma unroll
            for (int r = 0; r < 4; ++r) {
                float v0 = a0[r] + bv; v0 = v0 > 0.f ? v0 : 0.f;
                float v1 = a1[r] + bv; v1 = v1 > 0.f ? v1 : 0.f;
                hout[(size_t)(rb + r) * NDIM + cgcol]      = f2bf(v0);
                hout[(size_t)(rb + 16 + r) * NDIM + cgcol] = f2bf(v1);
            }
        } else {
#pragma unroll
            for (int r = 0; r < 4; ++r) {
                int t0 = perm[rb + r];
                int t1 = perm[rb + 16 + r];
                if (t0 >= 0) atomicAdd(&out[(size_t)t0 * DD + cgcol], a0[r]);
                if (t1 >= 0) atomicAdd(&out[(size_t)t1 * DD + cgcol], a1[r]);
            }
        }
    }
}

extern "C" void kernel_launch(void* const* d_in, const int* in_sizes, int n_in,
                              void* d_out, int out_size, void* d_ws, size_t ws_size,
                              hipStream_t stream) {
    const float* x    = (const float*)d_in[0];
    const int*   orig = (const int*)d_in[1];
    const int*   hmap = (const int*)d_in[2];
    const float* W1   = (const float*)d_in[3];
    const float* b1   = (const float*)d_in[4];
    const float* W2   = (const float*)d_in[5];
    const float* b2   = (const float*)d_in[6];
    float* out = (float*)d_out;

    int* hdr = (int*)d_ws;
    unsigned short* xp   = (unsigned short*)((char*)d_ws + 16384);
    unsigned short* hbuf = (unsigned short*)((char*)d_ws + 16384 + (size_t)RP_CAP * DD * 2);

    k_route<<<1, 256, 0, stream>>>(orig, hmap, hdr);
    k_gather<<<RP_CAP, 256, 0, stream>>>(x, hdr, xp);
    k_init<<<TOKENS, 256, 0, stream>>>(orig, hmap, b2, out);
    // GEMM1: 32 col-panels x 8 experts; weights hit HBM exactly once
    k_panel<DD, HH, 1, false><<<dim3(HH / 64, NE), 512, 0, stream>>>(xp, W1, b1, hdr, hbuf, nullptr);
    // GEMM2: 16 col-panels x (8 experts x 2 K-splits); atomic f32 partials onto bias-seeded out
    k_panel<HH, DD, 2, true><<<dim3(DD / 64, NE * 2), 512, 0, stream>>>(hbuf, W2, nullptr, hdr, nullptr, out);
}